// Round 4
// baseline (421.100 us; speedup 1.0000x reference)
//
#include <hip/hip_runtime.h>

#define NROWS 8192
#define DIN   64
#define DMID  1024
#define DOUT  64
#define NDOM  4
#define PADROWS 9216     // >= 8192 + 4*255 rounded to 256
#define MAXT256 36
#define MAXT128 68

typedef _Float16 half8 __attribute__((ext_vector_type(8)));
typedef _Float16 half4v __attribute__((ext_vector_type(4)));
typedef float floatx4 __attribute__((ext_vector_type(4)));

__device__ __forceinline__ void gload16(const void* g, void* l) {
  __builtin_amdgcn_global_load_lds((const __attribute__((address_space(1))) void*)g,
                                   (__attribute__((address_space(3))) void*)l, 16, 0, 0);
}

// ---------------- conversion kernels ----------------

__global__ void cast_f32_to_f16(const float* __restrict__ src, _Float16* __restrict__ dst, int n4) {
  int i = blockIdx.x * blockDim.x + threadIdx.x;
  if (i < n4) {
    float4 v = reinterpret_cast<const float4*>(src)[i];
    half4v o;
    o[0] = (_Float16)v.x; o[1] = (_Float16)v.y; o[2] = (_Float16)v.z; o[3] = (_Float16)v.w;
    reinterpret_cast<half4v*>(dst)[i] = o;
  }
}

// fused multi-matrix transpose+cast: [b][R][C] f32 -> [b][C][R] f16, 64x64 tiles
struct TDesc { const float* src; _Float16* dst; int R, C, tpb, batch, ofs; };
struct TPack { TDesc d[8]; };

__global__ void transpose_cast_multi(TPack p) {
  const int g = blockIdx.x;
  int i = 0;
#pragma unroll
  for (int j = 1; j < 8; ++j)
    if (g >= p.d[j].ofs) i = j;
  const TDesc D = p.d[i];
  const int local = g - D.ofs;
  const int b  = local / D.tpb;
  const int tx = local - b * D.tpb;
  const int cpr = D.C >> 6;
  const int c0 = (tx % cpr) * 64;
  const int r0 = (tx / cpr) * 64;
  const float* src = D.src + (size_t)b * D.R * D.C;
  _Float16*    dst = D.dst + (size_t)b * D.R * D.C;

  __shared__ float tile[64][65];
  const int t = threadIdx.x;
  const int x = t & 63;
  const int y4 = t >> 6;
#pragma unroll
  for (int k = 0; k < 16; ++k) {
    int r = y4 * 16 + k;
    tile[r][x] = src[(size_t)(r0 + r) * D.C + (c0 + x)];
  }
  __syncthreads();
#pragma unroll
  for (int k = 0; k < 16; ++k) {
    int c = y4 * 16 + k;
    dst[(size_t)(c0 + c) * D.R + (r0 + x)] = (_Float16)tile[x][c];
  }
}

// ---------------- routing setup ----------------
// meta (256-gran): [0]=T, [8+t]=dom, [80+t]=base
// meta+512 (128-gran): [0]=T2, [8+t]=dom, [80+t]=base, [160+t]=valid
__global__ void setup_kernel(const int* __restrict__ domains, int* __restrict__ meta,
                             int* __restrict__ sortpos, int* __restrict__ invperm) {
  __shared__ int cnt[NDOM];
  __shared__ int cur[NDOM];
  const int t = threadIdx.x;
  if (t < NDOM) cnt[t] = 0;
  __syncthreads();
  for (int i = t; i < NROWS; i += blockDim.x)
    atomicAdd(&cnt[domains[i]], 1);
  __syncthreads();
  if (t == 0) {
    int* m2 = meta + 512;
    int off = 0, T = 0, T2 = 0;
    for (int d = 0; d < NDOM; ++d) {
      cur[d] = off;
      int c = cnt[d];
      int nt = (c + 255) >> 8;
      for (int k = 0; k < nt; ++k) {
        meta[8 + T]  = d;
        meta[80 + T] = off + k * 256;
        ++T;
      }
      int nt2 = (c + 127) >> 7;
      for (int k = 0; k < nt2; ++k) {
        m2[8 + T2]   = d;
        m2[80 + T2]  = off + k * 128;
        int rem = c - k * 128;
        m2[160 + T2] = rem > 128 ? 128 : rem;
        ++T2;
      }
      off += nt * 256;
    }
    meta[0] = T;
    m2[0]   = T2;
  }
  __syncthreads();
  for (int i = t; i < NROWS; i += blockDim.x) {
    int d = domains[i];
    int p = atomicAdd(&cur[d], 1);
    sortpos[i] = p;
    invperm[p] = i;
  }
}

// ---------------- small GEMM (layer 1 K=64, final layer N=64) ----------------
template<int BN, int NKT, bool RELU, int IN_MODE, int OUT_MODE>
__global__ __launch_bounds__(256, 2)
void gemm_f16(const _Float16* __restrict__ A, const _Float16* __restrict__ Bt,
              const float* __restrict__ bias,
              _Float16* __restrict__ Ch, float* __restrict__ Cf,
              const int* __restrict__ meta, const int* __restrict__ sortpos,
              const int* __restrict__ invperm, int ldC) {
  constexpr int BM = 128, BK = 64;
  constexpr int K = NKT * BK;
  constexpr int NFN = BN / 32;
  const int tid = threadIdx.x;
  const int lane = tid & 63, wv = tid >> 6;
  const int lr = lane & 15, lk = lane >> 4;
  const int wr = wv >> 1, wc = wv & 1;

  int rowbase, valid = BM;
  if constexpr (IN_MODE == 1) {
    const int T = meta[0];
    if ((int)blockIdx.y >= T) return;
    const int dom = meta[8 + blockIdx.y];
    rowbase = meta[80 + blockIdx.y];
    valid   = meta[160 + blockIdx.y];
    Bt   += (size_t)dom * ldC * K;
    bias += (size_t)dom * ldC;
  } else {
    rowbase = blockIdx.y * BM;
  }
  const int n0 = blockIdx.x * BN;

  __shared__ __align__(16) unsigned char sA[BM * BK * 2];
  __shared__ __align__(16) unsigned char sB[BN * BK * 2];

  floatx4 acc[4][NFN];
#pragma unroll
  for (int i = 0; i < 4; ++i)
#pragma unroll
    for (int j = 0; j < NFN; ++j)
      acc[i][j] = (floatx4){0.f, 0.f, 0.f, 0.f};

  const unsigned char* Ab = (const unsigned char*)A + (size_t)rowbase * K * 2;
  const unsigned char* Bb = (const unsigned char*)Bt + (size_t)n0 * K * 2;

  for (int kt = 0; kt < NKT; ++kt) {
    const int kbyte0 = kt * BK * 2;
#pragma unroll
    for (int i = 0; i < 4; ++i) {
      int lo = (wv * 4 + i) * 1024 + lane * 16;
      int row = lo >> 7;
      int kb = lo & 127;
      int gkb = kb ^ ((row & 7) << 4);
      gload16(Ab + (size_t)row * (K * 2) + kbyte0 + gkb, sA + lo);
    }
#pragma unroll
    for (int i = 0; i < BN / 32; ++i) {
      int lo = (wv * (BN / 32) + i) * 1024 + lane * 16;
      int row = lo >> 7;
      int kb = lo & 127;
      int gkb = kb ^ ((row & 7) << 4);
      gload16(Bb + (size_t)row * (K * 2) + kbyte0 + gkb, sB + lo);
    }
    __syncthreads();

#pragma unroll
    for (int kk = 0; kk < 2; ++kk) {
      half8 af[4], bf[NFN];
#pragma unroll
      for (int fm = 0; fm < 4; ++fm) {
        int row = wr * 64 + fm * 16 + lr;
        int kb = kk * 64 + lk * 16;
        int addr = row * 128 + (kb ^ ((row & 7) << 4));
        af[fm] = *(const half8*)(sA + addr);
      }
#pragma unroll
      for (int fn = 0; fn < NFN; ++fn) {
        int row = wc * (BN / 2) + fn * 16 + lr;
        int kb = kk * 64 + lk * 16;
        int addr = row * 128 + (kb ^ ((row & 7) << 4));
        bf[fn] = *(const half8*)(sB + addr);
      }
#pragma unroll
      for (int fm = 0; fm < 4; ++fm)
#pragma unroll
        for (int fn = 0; fn < NFN; ++fn)
          acc[fm][fn] = __builtin_amdgcn_mfma_f32_16x16x32_f16(af[fm], bf[fn], acc[fm][fn], 0, 0, 0);
    }
    __syncthreads();
  }

  const int colbase = n0 + wc * (BN / 2);
#pragma unroll
  for (int fn = 0; fn < NFN; ++fn) {
    const int col = colbase + fn * 16 + lr;
    const float bv = bias[col];
#pragma unroll
    for (int fm = 0; fm < 4; ++fm) {
      const int rl = wr * 64 + fm * 16 + lk * 4;
#pragma unroll
      for (int r = 0; r < 4; ++r) {
        float v = acc[fm][fn][r] + bv;
        if (RELU) v = v > 0.f ? v : 0.f;
        const int row = rl + r;
        if constexpr (OUT_MODE == 0) {
          Ch[(size_t)(rowbase + row) * ldC + col] = (_Float16)v;
        } else if constexpr (OUT_MODE == 1) {
          const int orow = sortpos[rowbase + row];
          Ch[(size_t)orow * ldC + col] = (_Float16)v;
        } else {
          if (row < valid) {
            const int orow = invperm[rowbase + row];
            Cf[(size_t)orow * ldC + col] = v;
          }
        }
      }
    }
  }
}

// ---------------- big GEMM (K=1024): A in registers, B in LDS ----------------
// BM=256 x BN=128 x BK=64, 512 thr = 8 waves (4M x 2N), per-wave 64x64.
// A fragments loaded global->reg per wave (elastic, compiler-waited, 1-tile
// prefetch, ping-pong regs). B double-buffered in 2x16KB LDS via gload_lds.
// ONE barrier + ONE counted vmcnt(8) per K-tile (B stage = 2 loads issued
// BEFORE the 8 A loads, so vmcnt(8) drains exactly the B stage).
template<int IN_MODE, int OUT_MODE>
__global__ __launch_bounds__(512, 2)
void gemm_areg(const _Float16* __restrict__ A, const _Float16* __restrict__ Bt,
               const float* __restrict__ bias, _Float16* __restrict__ Ch,
               const int* __restrict__ meta, const int* __restrict__ sortpos,
               int chunk) {
  constexpr int K = DMID, NT = K / 64;   // 16
  __shared__ __align__(16) unsigned char sB[2 * 16384];

  const int tid  = threadIdx.x;
  const int lane = tid & 63;
  const int wv   = tid >> 6;
  const int lr = lane & 15, lk = lane >> 4;
  const int wr = wv >> 1, wc = wv & 1;

  // XCD swizzle: contiguous l-range per XCD -> one A-panel's 8 col-blocks share an L2
  const int bid = blockIdx.x;
  const int l  = (bid & 7) * chunk + (bid >> 3);
  const int by = l >> 3, bx = l & 7;

  int rowbase;
  const _Float16* Bt2 = Bt;
  const float* bias2 = bias;
  if constexpr (IN_MODE == 1) {
    if (by >= meta[0]) return;
    const int dom = meta[8 + by];
    rowbase = meta[80 + by];
    Bt2   += (size_t)dom * DMID * K;
    bias2 += (size_t)dom * DMID;
  } else {
    rowbase = by * 256;
  }
  const int n0 = bx * 128;

  const unsigned char* Ab = (const unsigned char*)A + (size_t)rowbase * (K * 2);
  const unsigned char* Bb = (const unsigned char*)Bt2 + (size_t)n0 * (K * 2);

  floatx4 acc[4][4];
#pragma unroll
  for (int i = 0; i < 4; ++i)
#pragma unroll
    for (int j = 0; j < 4; ++j)
      acc[i][j] = (floatx4){0.f, 0.f, 0.f, 0.f};

  half8 afA[4][2], afB[4][2];

  auto stageB = [&](int t) {   // B(t) -> slot t&1 ; 2 gload16 per thread
    unsigned char* dst = sB + (t & 1) * 16384;
    const unsigned char* src = Bb + t * 128;
#pragma unroll
    for (int i = 0; i < 2; ++i) {
      int lo = i * 8192 + tid * 16;
      int r = lo >> 7, kb = lo & 127;
      gload16(src + (size_t)r * 2048 + (kb ^ ((r & 7) << 4)), dst + lo);
    }
  };
  auto loadA = [&](int t, half8 (&dst)[4][2]) {  // A(t) -> regs, 8 loads per thread
#pragma unroll
    for (int fm = 0; fm < 4; ++fm) {
      const int row = wr * 64 + fm * 16 + lr;
#pragma unroll
      for (int kk = 0; kk < 2; ++kk)
        dst[fm][kk] = *(const half8*)(Ab + (size_t)row * 2048 + t * 128 + kk * 64 + lk * 16);
    }
  };
  auto body = [&](int t, half8 (&cur)[4][2], half8 (&nxt)[4][2]) {
    // read B fragments for tile t (swizzled)
    half8 bf[4][2];
#pragma unroll
    for (int fn = 0; fn < 4; ++fn) {
      const int row = wc * 64 + fn * 16 + lr;
      const unsigned char* base = sB + (t & 1) * 16384 + row * 128;
#pragma unroll
      for (int kk = 0; kk < 2; ++kk) {
        const int kb = kk * 64 + lk * 16;
        bf[fn][kk] = *(const half8*)(base + (kb ^ ((row & 7) << 4)));
      }
    }
    const bool more = (t + 1 < NT);
    if (more) {
      stageB(t + 1);        // 2 vmem (issued first)
      loadA(t + 1, nxt);    // 8 vmem (newer)
    }
    __builtin_amdgcn_s_setprio(1);
#pragma unroll
    for (int kk = 0; kk < 2; ++kk)
#pragma unroll
      for (int fm = 0; fm < 4; ++fm)
#pragma unroll
        for (int fn = 0; fn < 4; ++fn)
          acc[fm][fn] = __builtin_amdgcn_mfma_f32_16x16x32_f16(cur[fm][kk], bf[fn][kk], acc[fm][fn], 0, 0, 0);
    __builtin_amdgcn_s_setprio(0);
    if (more) {
      asm volatile("s_waitcnt vmcnt(8)" ::: "memory");  // drains B(t+1); A(t+1) stays in flight
      __builtin_amdgcn_s_barrier();
      asm volatile("" ::: "memory");
    }
  };

  // prologue: B(0) then A(0); vmcnt(8) drains B(0); publish
  stageB(0);
  loadA(0, afA);
  asm volatile("s_waitcnt vmcnt(8)" ::: "memory");
  __builtin_amdgcn_s_barrier();
  asm volatile("" ::: "memory");

#pragma unroll
  for (int t = 0; t < NT; ++t) {
    if (t & 1) body(t, afB, afA);
    else       body(t, afA, afB);
  }

  // epilogue: bias + relu, fp16 store
  const int colbase = n0 + wc * 64;
#pragma unroll
  for (int fn = 0; fn < 4; ++fn) {
    const int col = colbase + fn * 16 + lr;
    const float bv = bias2[col];
#pragma unroll
    for (int fm = 0; fm < 4; ++fm) {
      const int rl = wr * 64 + fm * 16 + lk * 4;
#pragma unroll
      for (int r = 0; r < 4; ++r) {
        float v = acc[fm][fn][r] + bv;
        v = v > 0.f ? v : 0.f;
        const int row = rowbase + rl + r;
        if constexpr (OUT_MODE == 0) {
          Ch[(size_t)row * DMID + col] = (_Float16)v;
        } else {
          const int orow = sortpos[row];
          Ch[(size_t)orow * DMID + col] = (_Float16)v;
        }
      }
    }
  }
}

// ---------------- launch ----------------

extern "C" void kernel_launch(void* const* d_in, const int* in_sizes, int n_in,
                              void* d_out, int out_size, void* d_ws, size_t ws_size,
                              hipStream_t stream) {
  const float* X   = (const float*)d_in[0];
  const int* domains = (const int*)d_in[1];
  const float* W1  = (const float*)d_in[2];
  const float* b1  = (const float*)d_in[3];
  const float* W2  = (const float*)d_in[4];
  const float* b2  = (const float*)d_in[5];
  const float* W3  = (const float*)d_in[6];
  const float* b3  = (const float*)d_in[7];
  const float* W4  = (const float*)d_in[8];
  const float* b4  = (const float*)d_in[9];
  const float* BW1 = (const float*)d_in[10];
  const float* Bb1 = (const float*)d_in[11];
  const float* BW2 = (const float*)d_in[12];
  const float* Bb2 = (const float*)d_in[13];
  const float* BW3 = (const float*)d_in[14];
  const float* Bb3 = (const float*)d_in[15];
  const float* BW4 = (const float*)d_in[16];
  const float* Bb4 = (const float*)d_in[17];
  float* out = (float*)d_out;

  char* base = (char*)d_ws;
  size_t off = 0;
  auto alloc = [&](size_t bytes) -> void* {
    void* p = base + off;
    off = (off + bytes + 255) & ~(size_t)255;
    return p;
  };
  _Float16* Xh   = (_Float16*)alloc((size_t)NROWS * DIN * 2);
  _Float16* W1t  = (_Float16*)alloc((size_t)DMID * DIN * 2);
  _Float16* W2t  = (_Float16*)alloc((size_t)DMID * DMID * 2);
  _Float16* W3t  = (_Float16*)alloc((size_t)DMID * DMID * 2);
  _Float16* W4t  = (_Float16*)alloc((size_t)DMID * DMID * 2);
  _Float16* BW1t = (_Float16*)alloc((size_t)NDOM * DMID * DMID * 2);
  _Float16* BW2t = (_Float16*)alloc((size_t)NDOM * DMID * DMID * 2);
  _Float16* BW3t = (_Float16*)alloc((size_t)NDOM * DMID * DMID * 2);
  _Float16* BW4t = (_Float16*)alloc((size_t)NDOM * DOUT * DMID * 2);
  _Float16* bufA = (_Float16*)alloc((size_t)NROWS * DMID * 2);
  _Float16* bufS0= (_Float16*)alloc((size_t)PADROWS * DMID * 2);
  _Float16* bufS1= (_Float16*)alloc((size_t)PADROWS * DMID * 2);
  int* sortpos   = (int*)alloc((size_t)NROWS * 4);
  int* invperm   = (int*)alloc((size_t)PADROWS * 4);
  int* meta      = (int*)alloc(1024 * 4);
  int* meta2     = meta + 512;

  // X cast
  cast_f32_to_f16<<<dim3((NROWS * DIN / 4 + 255) / 256), 256, 0, stream>>>(X, Xh, NROWS * DIN / 4);

  // fused weight transpose+cast (8 matrices, 3920 tile-blocks total)
  TPack tp;
  tp.d[0] = {W1,  W1t,  DIN,  DMID, (DIN/64)*(DMID/64),  1,    0};
  tp.d[1] = {W2,  W2t,  DMID, DMID, (DMID/64)*(DMID/64), 1,   16};
  tp.d[2] = {W3,  W3t,  DMID, DMID, (DMID/64)*(DMID/64), 1,  272};
  tp.d[3] = {W4,  W4t,  DMID, DMID, (DMID/64)*(DMID/64), 1,  528};
  tp.d[4] = {BW1, BW1t, DMID, DMID, (DMID/64)*(DMID/64), NDOM, 784};
  tp.d[5] = {BW2, BW2t, DMID, DMID, (DMID/64)*(DMID/64), NDOM, 1808};
  tp.d[6] = {BW3, BW3t, DMID, DMID, (DMID/64)*(DMID/64), NDOM, 2832};
  tp.d[7] = {BW4, BW4t, DMID, DOUT, (DMID/64)*(DOUT/64), NDOM, 3856};
  transpose_cast_multi<<<3920, 256, 0, stream>>>(tp);

  setup_kernel<<<1, 256, 0, stream>>>(domains, meta, sortpos, invperm);

  // layer 1 (K=64)
  gemm_f16<128, 1, true, 0, 0><<<dim3(DMID / 128, NROWS / 128), 256, 0, stream>>>(
      Xh, W1t, b1, bufA, nullptr, nullptr, nullptr, nullptr, DMID);

  // big K=1024 layers: A-in-reg kernel
  // dense: grid 256 = 32 row x 8 col (chunk 32); branch: grid 288 = 36 x 8 (chunk 36)
  gemm_areg<0, 0><<<256, 512, 0, stream>>>(bufA,  W2t, b2, bufS1, nullptr, nullptr, 32);
  gemm_areg<0, 0><<<256, 512, 0, stream>>>(bufS1, W3t, b3, bufA,  nullptr, nullptr, 32);
  gemm_areg<0, 1><<<256, 512, 0, stream>>>(bufA,  W4t, b4, bufS0, nullptr, sortpos, 32);
  gemm_areg<1, 0><<<8 * MAXT256, 512, 0, stream>>>(bufS0, BW1t, Bb1, bufS1, meta, nullptr, MAXT256);
  gemm_areg<1, 0><<<8 * MAXT256, 512, 0, stream>>>(bufS1, BW2t, Bb2, bufS0, meta, nullptr, MAXT256);
  gemm_areg<1, 0><<<8 * MAXT256, 512, 0, stream>>>(bufS0, BW3t, Bb3, bufS1, meta, nullptr, MAXT256);

  // final layer: fp32 scatter to d_out, no relu (128-gran tile map)
  gemm_f16<64, 16, false, 1, 2><<<dim3(1, MAXT128), 256, 0, stream>>>(
      bufS1, BW4t, Bb4, nullptr, out, meta2, nullptr, invperm, DOUT);
}

// Round 5
// 212.664 us; speedup vs baseline: 1.9801x; 1.9801x over previous
//
#include <hip/hip_runtime.h>

#define NROWS 8192
#define DIN   64
#define DMID  1024
#define DOUT  64
#define NDOM  4
#define PADROWS 9216
#define MAXT128 68

typedef _Float16 half8 __attribute__((ext_vector_type(8)));
typedef _Float16 half4v __attribute__((ext_vector_type(4)));
typedef float floatx4 __attribute__((ext_vector_type(4)));

__device__ __forceinline__ void gload16(const void* g, void* l) {
  __builtin_amdgcn_global_load_lds((const __attribute__((address_space(1))) void*)g,
                                   (__attribute__((address_space(3))) void*)l, 16, 0, 0);
}

// ---------------- conversion kernels ----------------

__global__ void cast_f32_to_f16(const float* __restrict__ src, _Float16* __restrict__ dst, int n4) {
  int i = blockIdx.x * blockDim.x + threadIdx.x;
  if (i < n4) {
    float4 v = reinterpret_cast<const float4*>(src)[i];
    half4v o;
    o[0] = (_Float16)v.x; o[1] = (_Float16)v.y; o[2] = (_Float16)v.z; o[3] = (_Float16)v.w;
    reinterpret_cast<half4v*>(dst)[i] = o;
  }
}

// fused multi-matrix transpose+cast: [b][R][C] f32 -> [b][C][R] f16, 64x64 tiles
struct TDesc { const float* src; _Float16* dst; int R, C, tpb, batch, ofs; };
struct TPack { TDesc d[8]; };

__global__ void transpose_cast_multi(TPack p) {
  const int g = blockIdx.x;
  int i = 0;
#pragma unroll
  for (int j = 1; j < 8; ++j)
    if (g >= p.d[j].ofs) i = j;
  const TDesc D = p.d[i];
  const int local = g - D.ofs;
  const int b  = local / D.tpb;
  const int tx = local - b * D.tpb;
  const int cpr = D.C >> 6;
  const int c0 = (tx % cpr) * 64;
  const int r0 = (tx / cpr) * 64;
  const float* src = D.src + (size_t)b * D.R * D.C;
  _Float16*    dst = D.dst + (size_t)b * D.R * D.C;

  __shared__ float tile[64][65];
  const int t = threadIdx.x;
  const int x = t & 63;
  const int y4 = t >> 6;
#pragma unroll
  for (int k = 0; k < 16; ++k) {
    int r = y4 * 16 + k;
    tile[r][x] = src[(size_t)(r0 + r) * D.C + (c0 + x)];
  }
  __syncthreads();
#pragma unroll
  for (int k = 0; k < 16; ++k) {
    int c = y4 * 16 + k;
    dst[(size_t)(c0 + c) * D.R + (r0 + x)] = (_Float16)tile[x][c];
  }
}

// ---------------- routing setup ----------------
// meta+512 (128-gran): [0]=T2, [8+t]=dom, [80+t]=base, [160+t]=valid
__global__ void setup_kernel(const int* __restrict__ domains, int* __restrict__ meta,
                             int* __restrict__ sortpos, int* __restrict__ invperm) {
  __shared__ int cnt[NDOM];
  __shared__ int cur[NDOM];
  const int t = threadIdx.x;
  if (t < NDOM) cnt[t] = 0;
  __syncthreads();
  for (int i = t; i < NROWS; i += blockDim.x)
    atomicAdd(&cnt[domains[i]], 1);
  __syncthreads();
  if (t == 0) {
    int* m2 = meta + 512;
    int off = 0, T2 = 0;
    for (int d = 0; d < NDOM; ++d) {
      cur[d] = off;
      int c = cnt[d];
      int nt2 = (c + 127) >> 7;
      for (int k = 0; k < nt2; ++k) {
        m2[8 + T2]   = d;
        m2[80 + T2]  = off + k * 128;
        int rem = c - k * 128;
        m2[160 + T2] = rem > 128 ? 128 : rem;
        ++T2;
      }
      off += ((c + 255) >> 8) * 256;   // keep 256-aligned domain segments
    }
    m2[0] = T2;
  }
  __syncthreads();
  for (int i = t; i < NROWS; i += blockDim.x) {
    int d = domains[i];
    int p = atomicAdd(&cur[d], 1);
    sortpos[i] = p;
    invperm[p] = i;
  }
}

// ---------------- small GEMM (layer 1 K=64, final layer N=64) ----------------
template<int BN, int NKT, bool RELU, int IN_MODE, int OUT_MODE>
__global__ __launch_bounds__(256, 2)
void gemm_f16(const _Float16* __restrict__ A, const _Float16* __restrict__ Bt,
              const float* __restrict__ bias,
              _Float16* __restrict__ Ch, float* __restrict__ Cf,
              const int* __restrict__ meta, const int* __restrict__ sortpos,
              const int* __restrict__ invperm, int ldC) {
  constexpr int BM = 128, BK = 64;
  constexpr int K = NKT * BK;
  constexpr int NFN = BN / 32;
  const int tid = threadIdx.x;
  const int lane = tid & 63, wv = tid >> 6;
  const int lr = lane & 15, lk = lane >> 4;
  const int wr = wv >> 1, wc = wv & 1;

  int rowbase, valid = BM;
  if constexpr (IN_MODE == 1) {
    const int T = meta[0];
    if ((int)blockIdx.y >= T) return;
    const int dom = meta[8 + blockIdx.y];
    rowbase = meta[80 + blockIdx.y];
    valid   = meta[160 + blockIdx.y];
    Bt   += (size_t)dom * ldC * K;
    bias += (size_t)dom * ldC;
  } else {
    rowbase = blockIdx.y * BM;
  }
  const int n0 = blockIdx.x * BN;

  __shared__ __align__(16) unsigned char sA[BM * BK * 2];
  __shared__ __align__(16) unsigned char sB[BN * BK * 2];

  floatx4 acc[4][NFN];
#pragma unroll
  for (int i = 0; i < 4; ++i)
#pragma unroll
    for (int j = 0; j < NFN; ++j)
      acc[i][j] = (floatx4){0.f, 0.f, 0.f, 0.f};

  const unsigned char* Ab = (const unsigned char*)A + (size_t)rowbase * K * 2;
  const unsigned char* Bb = (const unsigned char*)Bt + (size_t)n0 * K * 2;

  for (int kt = 0; kt < NKT; ++kt) {
    const int kbyte0 = kt * BK * 2;
#pragma unroll
    for (int i = 0; i < 4; ++i) {
      int lo = (wv * 4 + i) * 1024 + lane * 16;
      int row = lo >> 7;
      int kb = lo & 127;
      int gkb = kb ^ ((row & 7) << 4);
      gload16(Ab + (size_t)row * (K * 2) + kbyte0 + gkb, sA + lo);
    }
#pragma unroll
    for (int i = 0; i < BN / 32; ++i) {
      int lo = (wv * (BN / 32) + i) * 1024 + lane * 16;
      int row = lo >> 7;
      int kb = lo & 127;
      int gkb = kb ^ ((row & 7) << 4);
      gload16(Bb + (size_t)row * (K * 2) + kbyte0 + gkb, sB + lo);
    }
    __syncthreads();

#pragma unroll
    for (int kk = 0; kk < 2; ++kk) {
      half8 af[4], bf[NFN];
#pragma unroll
      for (int fm = 0; fm < 4; ++fm) {
        int row = wr * 64 + fm * 16 + lr;
        int kb = kk * 64 + lk * 16;
        int addr = row * 128 + (kb ^ ((row & 7) << 4));
        af[fm] = *(const half8*)(sA + addr);
      }
#pragma unroll
      for (int fn = 0; fn < NFN; ++fn) {
        int row = wc * (BN / 2) + fn * 16 + lr;
        int kb = kk * 64 + lk * 16;
        int addr = row * 128 + (kb ^ ((row & 7) << 4));
        bf[fn] = *(const half8*)(sB + addr);
      }
#pragma unroll
      for (int fm = 0; fm < 4; ++fm)
#pragma unroll
        for (int fn = 0; fn < NFN; ++fn)
          acc[fm][fn] = __builtin_amdgcn_mfma_f32_16x16x32_f16(af[fm], bf[fn], acc[fm][fn], 0, 0, 0);
    }
    __syncthreads();
  }

  const int colbase = n0 + wc * (BN / 2);
#pragma unroll
  for (int fn = 0; fn < NFN; ++fn) {
    const int col = colbase + fn * 16 + lr;
    const float bv = bias[col];
#pragma unroll
    for (int fm = 0; fm < 4; ++fm) {
      const int rl = wr * 64 + fm * 16 + lk * 4;
#pragma unroll
      for (int r = 0; r < 4; ++r) {
        float v = acc[fm][fn][r] + bv;
        if (RELU) v = v > 0.f ? v : 0.f;
        const int row = rl + r;
        if constexpr (OUT_MODE == 0) {
          Ch[(size_t)(rowbase + row) * ldC + col] = (_Float16)v;
        } else if constexpr (OUT_MODE == 1) {
          const int orow = sortpos[rowbase + row];
          Ch[(size_t)orow * ldC + col] = (_Float16)v;
        } else {
          if (row < valid) {
            const int orow = invperm[rowbase + row];
            Cf[(size_t)orow * ldC + col] = v;
          }
        }
      }
    }
  }
}

// ---------------- big GEMM (K=1024): 128x128x64, dbuf LDS, single barrier/iter ----------------
// 256 thr = 4 waves (2M x 2N), per-wave 64x64. LDS 2 slots x (A16K + B16K) = 64KB
// -> 2 blocks/CU (TLP). Pipeline: stage(t+1 -> slot^1) at TOP of iter t;
// ds_read + 32 MFMA on slot; vmcnt(0) + ONE barrier at bottom. MFMA's data
// dependency forces lgkmcnt on reads, so the barrier also retires all reads
// of `slot` before iter t+1 overwrites it. R1-proven XOR swizzle both sides.
template<int IN_MODE, int OUT_MODE>
__global__ __launch_bounds__(256, 2)
void gemm_mid(const _Float16* __restrict__ A, const _Float16* __restrict__ Bt,
              const float* __restrict__ bias, _Float16* __restrict__ Ch,
              const int* __restrict__ meta, const int* __restrict__ sortpos,
              int chunk) {
  constexpr int NT = 16;   // K=1024 / BK=64
  __shared__ __align__(16) unsigned char lds[2][32768];   // [slot][ A 16KB | B 16KB ]

  const int tid = threadIdx.x;
  const int lane = tid & 63, wv = tid >> 6;
  const int lr = lane & 15, lk = lane >> 4;
  const int wr = wv >> 1, wc = wv & 1;

  // XCD-aware bijective swizzle; grid = 8 * chunk
  const int bid = blockIdx.x;
  const int l  = (bid & 7) * chunk + (bid >> 3);
  const int by = l >> 3, bx = l & 7;

  int rowbase;
  const _Float16* Bt2 = Bt;
  const float* bias2 = bias;
  if constexpr (IN_MODE == 1) {
    if (by >= meta[0]) return;
    const int dom = meta[8 + by];
    rowbase = meta[80 + by];
    Bt2   += (size_t)dom * DMID * DMID;
    bias2 += (size_t)dom * DMID;
  } else {
    rowbase = by * 128;
  }
  const int n0 = bx * 128;

  const unsigned char* Ab = (const unsigned char*)A + (size_t)rowbase * 2048;
  const unsigned char* Bb = (const unsigned char*)Bt2 + (size_t)n0 * 2048;

  floatx4 acc[4][4];
#pragma unroll
  for (int i = 0; i < 4; ++i)
#pragma unroll
    for (int j = 0; j < 4; ++j)
      acc[i][j] = (floatx4){0.f, 0.f, 0.f, 0.f};

  // per-thread staging geometry (loop-invariant): 4 A-chunks + 4 B-chunks
  // chunk i covers LDS bytes lo = i*4096 + tid*16 ; row = lo>>7 ; kb = lo&127
  int srow[4], soff[4];   // source row and pre-swizzled k-byte for each i
#pragma unroll
  for (int i = 0; i < 4; ++i) {
    int lo = i * 4096 + tid * 16;
    srow[i] = lo >> 7;
    int kb = lo & 127;
    soff[i] = kb ^ ((srow[i] & 7) << 4);
  }

  auto stage = [&](int t, int s) {
    const int kb0 = t * 128;
#pragma unroll
    for (int i = 0; i < 4; ++i) {
      int lo = i * 4096 + tid * 16;
      gload16(Ab + (size_t)srow[i] * 2048 + kb0 + soff[i], &lds[s][lo]);
    }
#pragma unroll
    for (int i = 0; i < 4; ++i) {
      int lo = i * 4096 + tid * 16;
      gload16(Bb + (size_t)srow[i] * 2048 + kb0 + soff[i], &lds[s][16384 + lo]);
    }
  };

  // fragment LDS byte offsets (loop-invariant)
  int aoff[4][2], boff[4][2];
#pragma unroll
  for (int f = 0; f < 4; ++f) {
    int ra = wr * 64 + f * 16 + lr;
    int rb = wc * 64 + f * 16 + lr;
#pragma unroll
    for (int kk = 0; kk < 2; ++kk) {
      int kb = kk * 64 + lk * 16;
      aoff[f][kk] = ra * 128 + (kb ^ ((ra & 7) << 4));
      boff[f][kk] = 16384 + rb * 128 + (kb ^ ((rb & 7) << 4));
    }
  }

  stage(0, 0);
  asm volatile("s_waitcnt vmcnt(0)" ::: "memory");
  __builtin_amdgcn_s_barrier();
  asm volatile("" ::: "memory");

#pragma unroll
  for (int t = 0; t < NT; ++t) {
    const int s = t & 1;
    if (t + 1 < NT) stage(t + 1, s ^ 1);

    half8 af[4][2], bf[4][2];
#pragma unroll
    for (int f = 0; f < 4; ++f)
#pragma unroll
      for (int kk = 0; kk < 2; ++kk) {
        af[f][kk] = *(const half8*)(&lds[s][aoff[f][kk]]);
        bf[f][kk] = *(const half8*)(&lds[s][boff[f][kk]]);
      }

    __builtin_amdgcn_s_setprio(1);
#pragma unroll
    for (int kk = 0; kk < 2; ++kk)
#pragma unroll
      for (int fm = 0; fm < 4; ++fm)
#pragma unroll
        for (int fn = 0; fn < 4; ++fn)
          acc[fm][fn] = __builtin_amdgcn_mfma_f32_16x16x32_f16(af[fm][kk], bf[fn][kk], acc[fm][fn], 0, 0, 0);
    __builtin_amdgcn_s_setprio(0);

    if (t + 1 < NT) {
      asm volatile("s_waitcnt vmcnt(0)" ::: "memory");
      __builtin_amdgcn_s_barrier();
      asm volatile("" ::: "memory");
    }
  }

  // epilogue: bias + relu, fp16 store
  const int colbase = n0 + wc * 64;
#pragma unroll
  for (int fn = 0; fn < 4; ++fn) {
    const int col = colbase + fn * 16 + lr;
    const float bv = bias2[col];
#pragma unroll
    for (int fm = 0; fm < 4; ++fm) {
      const int rl = wr * 64 + fm * 16 + lk * 4;
#pragma unroll
      for (int r = 0; r < 4; ++r) {
        float v = acc[fm][fn][r] + bv;
        v = v > 0.f ? v : 0.f;
        const int row = rowbase + rl + r;
        if constexpr (OUT_MODE == 0) {
          Ch[(size_t)row * DMID + col] = (_Float16)v;
        } else {
          const int orow = sortpos[row];
          Ch[(size_t)orow * DMID + col] = (_Float16)v;
        }
      }
    }
  }
}

// ---------------- launch ----------------

extern "C" void kernel_launch(void* const* d_in, const int* in_sizes, int n_in,
                              void* d_out, int out_size, void* d_ws, size_t ws_size,
                              hipStream_t stream) {
  const float* X   = (const float*)d_in[0];
  const int* domains = (const int*)d_in[1];
  const float* W1  = (const float*)d_in[2];
  const float* b1  = (const float*)d_in[3];
  const float* W2  = (const float*)d_in[4];
  const float* b2  = (const float*)d_in[5];
  const float* W3  = (const float*)d_in[6];
  const float* b3  = (const float*)d_in[7];
  const float* W4  = (const float*)d_in[8];
  const float* b4  = (const float*)d_in[9];
  const float* BW1 = (const float*)d_in[10];
  const float* Bb1 = (const float*)d_in[11];
  const float* BW2 = (const float*)d_in[12];
  const float* Bb2 = (const float*)d_in[13];
  const float* BW3 = (const float*)d_in[14];
  const float* Bb3 = (const float*)d_in[15];
  const float* BW4 = (const float*)d_in[16];
  const float* Bb4 = (const float*)d_in[17];
  float* out = (float*)d_out;

  char* base = (char*)d_ws;
  size_t off = 0;
  auto alloc = [&](size_t bytes) -> void* {
    void* p = base + off;
    off = (off + bytes + 255) & ~(size_t)255;
    return p;
  };
  _Float16* Xh   = (_Float16*)alloc((size_t)NROWS * DIN * 2);
  _Float16* W1t  = (_Float16*)alloc((size_t)DMID * DIN * 2);
  _Float16* W2t  = (_Float16*)alloc((size_t)DMID * DMID * 2);
  _Float16* W3t  = (_Float16*)alloc((size_t)DMID * DMID * 2);
  _Float16* W4t  = (_Float16*)alloc((size_t)DMID * DMID * 2);
  _Float16* BW1t = (_Float16*)alloc((size_t)NDOM * DMID * DMID * 2);
  _Float16* BW2t = (_Float16*)alloc((size_t)NDOM * DMID * DMID * 2);
  _Float16* BW3t = (_Float16*)alloc((size_t)NDOM * DMID * DMID * 2);
  _Float16* BW4t = (_Float16*)alloc((size_t)NDOM * DOUT * DMID * 2);
  _Float16* bufA = (_Float16*)alloc((size_t)NROWS * DMID * 2);
  _Float16* bufS0= (_Float16*)alloc((size_t)PADROWS * DMID * 2);
  _Float16* bufS1= (_Float16*)alloc((size_t)PADROWS * DMID * 2);
  int* sortpos   = (int*)alloc((size_t)NROWS * 4);
  int* invperm   = (int*)alloc((size_t)PADROWS * 4);
  int* meta      = (int*)alloc(1024 * 4);
  int* meta2     = meta + 512;

  // X cast
  cast_f32_to_f16<<<dim3((NROWS * DIN / 4 + 255) / 256), 256, 0, stream>>>(X, Xh, NROWS * DIN / 4);

  // fused weight transpose+cast (8 matrices, 3920 tile-blocks total)
  TPack tp;
  tp.d[0] = {W1,  W1t,  DIN,  DMID, (DIN/64)*(DMID/64),  1,    0};
  tp.d[1] = {W2,  W2t,  DMID, DMID, (DMID/64)*(DMID/64), 1,   16};
  tp.d[2] = {W3,  W3t,  DMID, DMID, (DMID/64)*(DMID/64), 1,  272};
  tp.d[3] = {W4,  W4t,  DMID, DMID, (DMID/64)*(DMID/64), 1,  528};
  tp.d[4] = {BW1, BW1t, DMID, DMID, (DMID/64)*(DMID/64), NDOM, 784};
  tp.d[5] = {BW2, BW2t, DMID, DMID, (DMID/64)*(DMID/64), NDOM, 1808};
  tp.d[6] = {BW3, BW3t, DMID, DMID, (DMID/64)*(DMID/64), NDOM, 2832};
  tp.d[7] = {BW4, BW4t, DMID, DOUT, (DMID/64)*(DOUT/64), NDOM, 3856};
  transpose_cast_multi<<<3920, 256, 0, stream>>>(tp);

  setup_kernel<<<1, 256, 0, stream>>>(domains, meta, sortpos, invperm);

  // layer 1 (K=64)
  gemm_f16<128, 1, true, 0, 0><<<dim3(DMID / 128, NROWS / 128), 256, 0, stream>>>(
      Xh, W1t, b1, bufA, nullptr, nullptr, nullptr, nullptr, DMID);

  // big K=1024 layers: dense grid 512 (64 row-tiles x 8 col), chunk 64
  gemm_mid<0, 0><<<512, 256, 0, stream>>>(bufA,  W2t, b2, bufS1, nullptr, nullptr, 64);
  gemm_mid<0, 0><<<512, 256, 0, stream>>>(bufS1, W3t, b3, bufA,  nullptr, nullptr, 64);
  gemm_mid<0, 1><<<512, 256, 0, stream>>>(bufA,  W4t, b4, bufS0, nullptr, sortpos, 64);
  // branch layers: grid 544 (68 x 8), chunk 68, 128-gran tile map
  gemm_mid<1, 0><<<544, 256, 0, stream>>>(bufS0, BW1t, Bb1, bufS1, meta2, nullptr, MAXT128);
  gemm_mid<1, 0><<<544, 256, 0, stream>>>(bufS1, BW2t, Bb2, bufS0, meta2, nullptr, MAXT128);
  gemm_mid<1, 0><<<544, 256, 0, stream>>>(bufS0, BW3t, Bb3, bufS1, meta2, nullptr, MAXT128);

  // final layer: fp32 scatter to d_out, no relu (128-gran tile map)
  gemm_f16<64, 16, false, 1, 2><<<dim3(1, MAXT128), 256, 0, stream>>>(
      bufS1, BW4t, Bb4, nullptr, out, meta2, nullptr, invperm, DOUT);
}